// Round 5
// baseline (540.216 us; speedup 1.0000x reference)
//
#include <hip/hip_runtime.h>
#include <math.h>

// Problem constants (match reference)
#define NN 50000
#define NE 800000
#define DIN 256
#define HH 128      // H1 == H2 == 128
#define DOUT 40
#define NN_PAD 50176   // NN rounded to 256

// ---------------------------------------------------------------------------
// CSR build step 1: in-degree count (self-loop handled as +1 later)
__global__ __launch_bounds__(256) void k_cnt(const int* __restrict__ dst,
                                             int* __restrict__ cnt) {
    int e = blockIdx.x * 256 + threadIdx.x;
    if (e < NE) atomicAdd(&cnt[dst[e]], 1);
}

// CSR build step 2a: per-256-block inclusive scan + block sums; fused dinv
__global__ __launch_bounds__(256) void scan_part(const int* __restrict__ cnt,
                                                 int* __restrict__ incl,
                                                 int* __restrict__ bsum,
                                                 float* __restrict__ dinv) {
    __shared__ int s[256];
    int t = threadIdx.x;
    int id = blockIdx.x * 256 + t;
    int c = cnt[id];                   // cnt padded to NN_PAD, pad = 0
    dinv[id] = rsqrtf((float)c + 1.0f);
    s[t] = c;
    __syncthreads();
    #pragma unroll
    for (int off = 1; off < 256; off <<= 1) {
        int v = (t >= off) ? s[t - off] : 0;
        __syncthreads();
        s[t] += v;
        __syncthreads();
    }
    incl[id] = s[t];
    if (t == 255) bsum[blockIdx.x] = s[255];
}

// CSR build step 2b: exclusive scan of block sums (single block, nb<=256)
__global__ __launch_bounds__(256) void scan_bsum(int* __restrict__ bsum, int nb) {
    __shared__ int s[256];
    int t = threadIdx.x;
    int orig = (t < nb) ? bsum[t] : 0;
    s[t] = orig;
    __syncthreads();
    #pragma unroll
    for (int off = 1; off < 256; off <<= 1) {
        int v = (t >= off) ? s[t - off] : 0;
        __syncthreads();
        s[t] += v;
        __syncthreads();
    }
    if (t < nb) bsum[t] = s[t] - orig;   // exclusive
}

// CSR build step 2c: global exclusive rowptr
__global__ __launch_bounds__(256) void scan_final(const int* __restrict__ incl,
                                                  const int* __restrict__ cnt,
                                                  const int* __restrict__ bsum,
                                                  int* __restrict__ rowptr) {
    int id = blockIdx.x * 256 + threadIdx.x;
    if (id < NN) rowptr[id] = incl[id] - cnt[id] + bsum[id >> 8];
    if (id == 0) rowptr[NN] = NE;
}

// CSR build step 3: fill (src index + precomputed edge norm)
__global__ __launch_bounds__(256) void fill_csr(
    const int* __restrict__ src, const int* __restrict__ dst,
    const float* __restrict__ dinv, const int* __restrict__ rowptr,
    int* __restrict__ cursor, int* __restrict__ csr_src,
    float* __restrict__ csr_norm) {
    int e = blockIdx.x * 256 + threadIdx.x;
    if (e >= NE) return;
    int s = src[e], d = dst[e];
    int pos = rowptr[d] + atomicAdd(&cursor[d], 1);
    csr_src[pos] = s;
    csr_norm[pos] = dinv[s] * dinv[d];
}

// ---------------------------------------------------------------------------
// Gather aggregation: out[d] = sum_{e: dst=d} h[src]*norm + h[d]*dinv[d]^2
//                     (+ bias) (+ optional relu).  32 lanes per node x float4.
// 2x unrolled edge loop: both index loads issued before both row loads (MLP).
__global__ __launch_bounds__(256) void gather_csr(
    const int* __restrict__ rowptr, const int* __restrict__ csr_src,
    const float* __restrict__ csr_norm, const float* __restrict__ dinv,
    const float* __restrict__ h, const float* __restrict__ bias,
    float* __restrict__ out, int relu) {
    long gid = (long)blockIdx.x * 256 + threadIdx.x;
    int node = (int)(gid >> 5);
    if (node >= NN) return;
    int lane = (int)(gid & 31);
    float dd = dinv[node];
    float sl = dd * dd;                                // self-loop norm
    const float4 hv = *reinterpret_cast<const float4*>(&h[(long)node * HH + lane * 4]);
    float4 acc;
    acc.x = hv.x * sl; acc.y = hv.y * sl; acc.z = hv.z * sl; acc.w = hv.w * sl;
    int beg = rowptr[node], end = rowptr[node + 1];
    int i = beg;
    for (; i + 2 <= end; i += 2) {
        int s0 = csr_src[i], s1 = csr_src[i + 1];
        float n0 = csr_norm[i], n1 = csr_norm[i + 1];
        const float4 v0 = *reinterpret_cast<const float4*>(&h[(long)s0 * HH + lane * 4]);
        const float4 v1 = *reinterpret_cast<const float4*>(&h[(long)s1 * HH + lane * 4]);
        acc.x += v0.x * n0; acc.y += v0.y * n0;
        acc.z += v0.z * n0; acc.w += v0.w * n0;
        acc.x += v1.x * n1; acc.y += v1.y * n1;
        acc.z += v1.z * n1; acc.w += v1.w * n1;
    }
    if (i < end) {
        int s0 = csr_src[i];
        float n0 = csr_norm[i];
        const float4 v0 = *reinterpret_cast<const float4*>(&h[(long)s0 * HH + lane * 4]);
        acc.x += v0.x * n0; acc.y += v0.y * n0;
        acc.z += v0.z * n0; acc.w += v0.w * n0;
    }
    const float4 bv = *reinterpret_cast<const float4*>(&bias[lane * 4]);
    acc.x += bv.x; acc.y += bv.y; acc.z += bv.z; acc.w += bv.w;
    if (relu) {
        acc.x = fmaxf(acc.x, 0.f); acc.y = fmaxf(acc.y, 0.f);
        acc.z = fmaxf(acc.z, 0.f); acc.w = fmaxf(acc.w, 0.f);
    }
    *reinterpret_cast<float4*>(&out[(long)node * HH + lane * 4]) = acc;
}

// ---------------------------------------------------------------------------
// Dual-batched f32 GEMM: blockIdx.y selects problem {0,1}. Each: C=A@B(+bias)(relu)
// 128x128 tile, BK=32, 256 threads, 8x8/thread, float4 LDS reads, As transposed.
// Doubles block count (2x391=782 on 256 CUs) to kill the 1.5-block/CU tail.
__global__ __launch_bounds__(256) void gemm128_dual(
    const float* __restrict__ A0, const float* __restrict__ B0,
    float* __restrict__ C0, const float* __restrict__ bias0, int relu0,
    const float* __restrict__ A1, const float* __restrict__ B1,
    float* __restrict__ C1, const float* __restrict__ bias1, int relu1,
    int M, int K, int Nw) {
    __shared__ float As[32][132];   // [k][row], stride 132 keeps b128 align
    __shared__ float Bs[32][132];   // [k][col]
    const float* A; const float* B; float* C; const float* bias; int relu;
    if (blockIdx.y == 0) { A = A0; B = B0; C = C0; bias = bias0; relu = relu0; }
    else                 { A = A1; B = B1; C = C1; bias = bias1; relu = relu1; }
    const int m0 = blockIdx.x * 128, n0 = 0;   // Nw == 128: single N tile
    const int tid = threadIdx.x;
    const int tr = tid >> 4, tc = tid & 15;   // 16x16 threads, 8x8 each
    float acc[8][8] = {};
    for (int k0 = 0; k0 < K; k0 += 32) {
        // stage A tile (128 rows x 32 k), transposed into As[k][row]
        #pragma unroll
        for (int p = 0; p < 4; p++) {
            int f = tid + 256 * p;            // 0..1023 float4 slots
            int row = f >> 3, kq = f & 7;     // 8 float4 per row
            float4 v = make_float4(0.f, 0.f, 0.f, 0.f);
            int grow = m0 + row;
            if (grow < M)
                v = *reinterpret_cast<const float4*>(&A[(long)grow * K + k0 + kq * 4]);
            As[kq * 4 + 0][row] = v.x;
            As[kq * 4 + 1][row] = v.y;
            As[kq * 4 + 2][row] = v.z;
            As[kq * 4 + 3][row] = v.w;
        }
        // stage B tile (32 k x 128 cols), row-major
        #pragma unroll
        for (int p = 0; p < 4; p++) {
            int f = tid + 256 * p;            // 0..1023 float4 slots
            int kk = f >> 5, nq = f & 31;
            float4 v = *reinterpret_cast<const float4*>(&B[(long)(k0 + kk) * Nw + n0 + nq * 4]);
            *reinterpret_cast<float4*>(&Bs[kk][nq * 4]) = v;
        }
        __syncthreads();
        #pragma unroll
        for (int k = 0; k < 32; k++) {
            const float4 a0 = *reinterpret_cast<const float4*>(&As[k][tr * 8]);
            const float4 a1 = *reinterpret_cast<const float4*>(&As[k][tr * 8 + 4]);
            const float4 b0 = *reinterpret_cast<const float4*>(&Bs[k][tc * 8]);
            const float4 b1 = *reinterpret_cast<const float4*>(&Bs[k][tc * 8 + 4]);
            const float a[8] = {a0.x, a0.y, a0.z, a0.w, a1.x, a1.y, a1.z, a1.w};
            const float b[8] = {b0.x, b0.y, b0.z, b0.w, b1.x, b1.y, b1.z, b1.w};
            #pragma unroll
            for (int i = 0; i < 8; i++)
                #pragma unroll
                for (int j = 0; j < 8; j++)
                    acc[i][j] += a[i] * b[j];
        }
        __syncthreads();
    }
    float bv[8];
    #pragma unroll
    for (int j = 0; j < 8; j++) bv[j] = bias ? bias[n0 + tc * 8 + j] : 0.f;
    #pragma unroll
    for (int i = 0; i < 8; i++) {
        int grow = m0 + tr * 8 + i;
        if (grow >= M) continue;
        float o[8];
        #pragma unroll
        for (int j = 0; j < 8; j++) {
            o[j] = acc[i][j] + bv[j];
            if (relu) o[j] = fmaxf(o[j], 0.f);
        }
        float* cp = &C[(long)grow * Nw + n0 + tc * 8];
        *reinterpret_cast<float4*>(cp)     = make_float4(o[0], o[1], o[2], o[3]);
        *reinterpret_cast<float4*>(cp + 4) = make_float4(o[4], o[5], o[6], o[7]);
    }
}

// ---------------------------------------------------------------------------
// Final fused: h = relu(concat(g2, hl2)); logits = h@Wf+bf; softmax.
// g2 already contains gcn2 sum + self-loop + bg2.
// Block = 256 thr = 64 nodes x 4 colgroups(10 cols).
__global__ __launch_bounds__(256) void final_fused(
    const float* __restrict__ g2, const float* __restrict__ hl2,
    const float* __restrict__ Wf, const float* __restrict__ bf,
    float* __restrict__ out) {
    __shared__ float WfS[2 * HH * DOUT];   // 256x40 = 40KB
    __shared__ float bfS[DOUT];
    __shared__ float hs[64][33];
    const int tid = threadIdx.x;
    for (int p = tid; p < 2 * HH * DOUT; p += 256) WfS[p] = Wf[p];
    if (tid < DOUT) bfS[tid] = bf[tid];
    const int node0 = blockIdx.x * 64;
    const int nl = tid >> 2;   // local node 0..63
    const int cg = tid & 3;    // col group: cols cg*10 .. +9
    float acc[10] = {};
    for (int kt = 0; kt < 8; kt++) {
        __syncthreads();
        #pragma unroll
        for (int p = 0; p < 8; p++) {   // stage h chunk [64][32]
            int id = tid + 256 * p;
            int r = id >> 5, c = id & 31;
            int gn = node0 + r;
            int f = kt * 32 + c;
            float v = 0.f;
            if (gn < NN) {
                if (f < HH) v = fmaxf(g2[(long)gn * HH + f], 0.f);
                else        v = fmaxf(hl2[(long)gn * HH + (f - HH)], 0.f);
            }
            hs[r][c] = v;
        }
        __syncthreads();
        #pragma unroll
        for (int k = 0; k < 32; k++) {
            float hv = hs[nl][k];
            const float* wrow = &WfS[(kt * 32 + k) * DOUT + cg * 10];
            #pragma unroll
            for (int j = 0; j < 10; j++) acc[j] += hv * wrow[j];
        }
    }
    #pragma unroll
    for (int j = 0; j < 10; j++) acc[j] += bfS[cg * 10 + j];
    // softmax over 40 = reduce across the 4 lanes of this node
    float m = acc[0];
    #pragma unroll
    for (int j = 1; j < 10; j++) m = fmaxf(m, acc[j]);
    m = fmaxf(m, __shfl_xor(m, 1));
    m = fmaxf(m, __shfl_xor(m, 2));
    float e[10], ssum = 0.f;
    #pragma unroll
    for (int j = 0; j < 10; j++) { e[j] = expf(acc[j] - m); ssum += e[j]; }
    ssum += __shfl_xor(ssum, 1);
    ssum += __shfl_xor(ssum, 2);
    float inv = 1.f / ssum;
    int gn = node0 + nl;
    if (gn < NN) {
        float* lo = out + (long)gn * DOUT + cg * 10;
        float* po = out + (long)NN * DOUT + (long)gn * DOUT + cg * 10;
        #pragma unroll
        for (int j = 0; j < 10; j++) { lo[j] = acc[j]; po[j] = e[j] * inv; }
    }
}

// ---------------------------------------------------------------------------
extern "C" void kernel_launch(void* const* d_in, const int* in_sizes, int n_in,
                              void* d_out, int out_size, void* d_ws, size_t ws_size,
                              hipStream_t stream) {
    const float* x   = (const float*)d_in[0];
    const int*   ei  = (const int*)d_in[1];
    const float* Wg1 = (const float*)d_in[2];
    const float* bg1 = (const float*)d_in[3];
    const float* Wg2 = (const float*)d_in[4];
    const float* bg2 = (const float*)d_in[5];
    const float* Wl1 = (const float*)d_in[6];
    const float* bl1 = (const float*)d_in[7];
    const float* Wl2 = (const float*)d_in[8];
    const float* bl2 = (const float*)d_in[9];
    const float* Wf  = (const float*)d_in[10];
    const float* bf  = (const float*)d_in[11];
    float* out = (float*)d_out;

    const int* src = ei;            // edge_index[0]
    const int* dst = ei + NE;       // edge_index[1]

    // Workspace layout. Floats first (16B aligned), then ints. ~110 MB.
    float* ws   = (float*)d_ws;
    float* dinv = ws;                         // NN_PAD
    float* hg   = dinv + NN_PAD;              // NN*HH   (x@Wg1; later hg2)
    float* hl   = hg + (long)NN * HH;         // NN*HH   (relu(x@Wl1+bl1))
    float* h1   = hl + (long)NN * HH;         // NN*HH   (gcn1 out; later g2)
    float* hl2  = h1 + (long)NN * HH;         // NN*HH
    float* csr_norm = hl2 + (long)NN * HH;    // NE
    int* cnt     = (int*)(csr_norm + NE);     // NN_PAD
    int* incl    = cnt + NN_PAD;              // NN_PAD
    int* bsum    = incl + NN_PAD;             // 256
    int* rowptr  = bsum + 256;                // NN_PAD (uses NN+1)
    int* cursor  = rowptr + NN_PAD;           // NN_PAD
    int* csr_src = cursor + NN_PAD;           // NE

    const int NB = NN_PAD / 256;              // 196

    // ---- CSR build (per call; ws is re-poisoned before every launch) ----
    hipMemsetAsync(cnt, 0, NN_PAD * sizeof(int), stream);
    hipMemsetAsync(cursor, 0, NN_PAD * sizeof(int), stream);
    k_cnt<<<(NE + 255) / 256, 256, 0, stream>>>(dst, cnt);
    scan_part<<<NB, 256, 0, stream>>>(cnt, incl, bsum, dinv);
    scan_bsum<<<1, 256, 0, stream>>>(bsum, NB);
    scan_final<<<NB, 256, 0, stream>>>(incl, cnt, bsum, rowptr);
    fill_csr<<<(NE + 255) / 256, 256, 0, stream>>>(src, dst, dinv, rowptr,
                                                   cursor, csr_src, csr_norm);

    // ---- Layer 1 GEMMs (batched): hg = x@Wg1 ; hl = relu(x@Wl1+bl1) ----
    dim3 g1((NN + 127) / 128, 2);
    gemm128_dual<<<g1, 256, 0, stream>>>(
        x, Wg1, hg, nullptr, 0,
        x, Wl1, hl, bl1, 1,
        NN, DIN, HH);

    // ---- GCN layer 1 aggregation (fused self-loop + bias + relu) ----
    gather_csr<<<(int)(((long)NN * 32 + 255) / 256), 256, 0, stream>>>(
        rowptr, csr_src, csr_norm, dinv, hg, bg1, h1, 1);

    // ---- Layer 2 GEMMs (batched): hg2 = h1@Wg2 ; hl2 = hl@Wl2+bl2 ----
    gemm128_dual<<<g1, 256, 0, stream>>>(
        h1, Wg2, hg, nullptr, 0,
        hl, Wl2, hl2, bl2, 0,
        NN, HH, HH);

    // ---- GCN layer 2 aggregation (fused self-loop + bg2, no relu) ----
    gather_csr<<<(int)(((long)NN * 32 + 255) / 256), 256, 0, stream>>>(
        rowptr, csr_src, csr_norm, dinv, hg, bg2, h1, 0);

    // ---- Final: concat + relu + [256->40] GEMM + softmax ----
    final_fused<<<(NN + 63) / 64, 256, 0, stream>>>(h1, hl2, Wf, bf, out);
}